// Round 6
// baseline (176.348 us; speedup 1.0000x reference)
//
#include <hip/hip_runtime.h>
#include <stdint.h>

#define GK 2048
#define GN 2048
#define GM 8192  // tokens = 4 * 2048

#define NVX (GM * (unsigned)GK / 4)   // 4,194,304 float4 in x
#define NVW (GN * (unsigned)GK / 4)   // 1,048,576 float4 in w

#define XBLK 1024  // absmax x-blocks: 16 iters exactly
#define WBLK 256   // absmax w-blocks: 16 iters exactly
#define QXBLK 4096 // quant x-blocks: 4 float4/thread exactly
#define QWBLK 1024 // quant w-blocks
#define NT (GK / 128)  // 16 K-tiles

typedef int i32x4 __attribute__((ext_vector_type(4)));

__device__ __forceinline__ float amax4(float4 v) {
    return fmaxf(fmaxf(fabsf(v.x), fabsf(v.y)), fmaxf(fabsf(v.z), fabsf(v.w)));
}

// ---------------------------------------------------------------------------
// Stage 1: per-block absmax partials (ILP-4, no atomics, no inner branch)
// ---------------------------------------------------------------------------
__global__ __launch_bounds__(256) void absmax_kernel(
    const float4* __restrict__ xv, const float4* __restrict__ wv,
    float* __restrict__ partial)
{
    const bool isx = blockIdx.x < XBLK;
    const float4* __restrict__ src = isx ? xv : wv;
    const unsigned n      = isx ? NVX : NVW;
    const unsigned b0     = isx ? blockIdx.x : blockIdx.x - XBLK;
    const unsigned stride = (isx ? XBLK : WBLK) * 256u;

    unsigned i = b0 * 256u + threadIdx.x;
    float m = 0.f;
    for (; i + 3u * stride < n; i += 4u * stride) {
        float4 a = src[i];
        float4 b = src[i + stride];
        float4 c = src[i + 2u * stride];
        float4 d = src[i + 3u * stride];
        m = fmaxf(m, fmaxf(fmaxf(amax4(a), amax4(b)),
                           fmaxf(amax4(c), amax4(d))));
    }
    for (; i < n; i += stride) m = fmaxf(m, amax4(src[i]));

    #pragma unroll
    for (int off = 32; off > 0; off >>= 1)
        m = fmaxf(m, __shfl_xor(m, off, 64));

    __shared__ float sm[4];
    const int wid = threadIdx.x >> 6;
    if ((threadIdx.x & 63) == 0) sm[wid] = m;
    __syncthreads();
    if (threadIdx.x == 0)
        partial[blockIdx.x] = fmaxf(fmaxf(sm[0], sm[1]), fmaxf(sm[2], sm[3]));
}

// ---------------------------------------------------------------------------
// Block-local reduce of the 1280 partials (x: [0,1024), w: [1024,1280)).
// ---------------------------------------------------------------------------
__device__ __forceinline__ void reduce_scales(const float* __restrict__ partial,
                                              int tid, float* ax_out, float* aw_out)
{
    __shared__ float smx[4], smw[4];
    float mx = 0.f, mw = 0.f;
    if (tid < 256) {
        mx = fmaxf(fmaxf(partial[tid], partial[tid + 256]),
                   fmaxf(partial[tid + 512], partial[tid + 768]));
        mw = partial[1024 + tid];
        #pragma unroll
        for (int off = 32; off > 0; off >>= 1) {
            mx = fmaxf(mx, __shfl_xor(mx, off, 64));
            mw = fmaxf(mw, __shfl_xor(mw, off, 64));
        }
        if ((tid & 63) == 0) { smx[tid >> 6] = mx; smw[tid >> 6] = mw; }
    }
    __syncthreads();
    *ax_out = fmaxf(fmaxf(smx[0], smx[1]), fmaxf(smx[2], smx[3]));
    *aw_out = fmaxf(fmaxf(smw[0], smw[1]), fmaxf(smw[2], smw[3]));
}

// ---------------------------------------------------------------------------
// Stage 2: quantize. Bit-exact: q = rintf(v / (absmax/127)), half-even,
// IEEE div, clip, cast. ILP-4, unit-stride loads and stores.
// ---------------------------------------------------------------------------
__device__ __forceinline__ signed char quant1(float v, float s) {
    float r = rintf(v / s);
    r = fminf(fmaxf(r, -128.f), 127.f);
    return (signed char)(int)r;
}

__device__ __forceinline__ char4 quantv(float4 v, float s) {
    char4 q;
    q.x = quant1(v.x, s); q.y = quant1(v.y, s);
    q.z = quant1(v.z, s); q.w = quant1(v.w, s);
    return q;
}

__global__ __launch_bounds__(256) void quant_kernel(
    const float4* __restrict__ xv, const float4* __restrict__ wv,
    const float* __restrict__ partial,
    char4* __restrict__ xq, char4* __restrict__ wq)
{
    float ax, aw;
    reduce_scales(partial, threadIdx.x, &ax, &aw);

    const bool isx = blockIdx.x < QXBLK;
    const float s = (isx ? ax : aw) / 127.0f;
    const float4* __restrict__ src = isx ? xv : wv;
    char4* __restrict__ dst        = isx ? xq : wq;
    const unsigned b0     = isx ? blockIdx.x : blockIdx.x - QXBLK;
    const unsigned stride = (isx ? QXBLK : QWBLK) * 256u;
    const unsigned t      = b0 * 256u + threadIdx.x;

    float4 a = src[t];
    float4 b = src[t + stride];
    float4 c = src[t + 2u * stride];
    float4 d = src[t + 3u * stride];
    dst[t]               = quantv(a, s);
    dst[t + stride]      = quantv(b, s);
    dst[t + 2u * stride] = quantv(c, s);
    dst[t + 3u * stride] = quantv(d, s);
}

// ---------------------------------------------------------------------------
// Stage 3: int8 GEMM — 256x256 tile, BK=128, 8 waves (2M x 4N), 4 quadrant
// phases/K-tile with COUNTED vmcnt (T4): stage 1 half-tile per phase in order
// B0,B1,A0,A1; waits are vmcnt(4)@ph1 (guards A1, 2 phases old) and
// vmcnt(2)@ph3 (guards B0,B1,A0 for next tile) — never 0 in the main loop.
// Wave fragments split across BOTH halves of A and B so each phase consumes
// only matured half-tiles:
//   A-frag m: row = (m<4 ? wr*64+m*16 : 128+wr*64+(m-4)*16)
//   B-frag n: row = (n<2 ? wc*32+n*16 : 128+wc*32+(n-2)*16)
// LDS 128KB dbuf, XOR swizzle (pre-swizzled source), mfma_i32_16x16x64_i8,
// T1 bijective XCD swizzle, fused dequant+bias epilogue.
// ---------------------------------------------------------------------------
__global__ __launch_bounds__(512, 2) void gemm_kernel(
    const signed char* __restrict__ Aq,
    const signed char* __restrict__ Bq,
    const float* __restrict__ bias,
    const float* __restrict__ partial,
    float* __restrict__ out)
{
    __shared__ signed char lds[131072];   // [2 bufs][A 32KB | B 32KB]

    const int tid  = threadIdx.x;
    const int lane = tid & 63;
    const int wid  = tid >> 6;       // 0..7
    const int wr   = wid >> 2;       // 0..1
    const int wc   = wid & 3;        // 0..3

    // T1 bijective XCD swizzle: 256 blocks, 8 XCDs, 32 consecutive wgids/XCD
    const int wgid = ((blockIdx.x & 7) << 5) | (blockIdx.x >> 3);
    const int bn   = wgid & 7;       // GN/256 = 8
    const int bm   = wgid >> 3;      // GM/256 = 32

    float ax, aw;
    reduce_scales(partial, tid, &ax, &aw);
    const float s = (ax / 127.0f) * (aw / 127.0f);

    // ---- staging: half-tile he (h=half, e=quarter) = 2 issues/thread ----
    const int srcslot = (tid & 7) ^ ((tid >> 3) & 7);
    const signed char* aSrc[4]; const signed char* bSrc[4];
    int aDst[4], bDst[4];
    #pragma unroll
    for (int he = 0; he < 4; ++he) {
        const int h = he >> 1, e = he & 1;
        const int r = h * 128 + e * 64 + (tid >> 3);
        aSrc[he] = Aq + (long)(bm * 256 + r) * GK + srcslot * 16;
        bSrc[he] = Bq + (long)(bn * 256 + r) * GK + srcslot * 16;
        aDst[he] = h * 16384 + e * 8192 + tid * 16;
        bDst[he] = 32768 + h * 16384 + e * 8192 + tid * 16;
    }

    #define STAGE_A(hh, buf, koff)                                             \
        { __builtin_amdgcn_global_load_lds(                                    \
              (const __attribute__((address_space(1))) void*)(aSrc[2*(hh)] + (koff)),   \
              (__attribute__((address_space(3))) void*)((buf) + aDst[2*(hh)]), 16,0,0); \
          __builtin_amdgcn_global_load_lds(                                    \
              (const __attribute__((address_space(1))) void*)(aSrc[2*(hh)+1] + (koff)), \
              (__attribute__((address_space(3))) void*)((buf) + aDst[2*(hh)+1]),16,0,0);}
    #define STAGE_B(hh, buf, koff)                                             \
        { __builtin_amdgcn_global_load_lds(                                    \
              (const __attribute__((address_space(1))) void*)(bSrc[2*(hh)] + (koff)),   \
              (__attribute__((address_space(3))) void*)((buf) + bDst[2*(hh)]), 16,0,0); \
          __builtin_amdgcn_global_load_lds(                                    \
              (const __attribute__((address_space(1))) void*)(bSrc[2*(hh)+1] + (koff)), \
              (__attribute__((address_space(3))) void*)((buf) + bDst[2*(hh)+1]),16,0,0);}

    // ---- ds_read constants ----
    const int lcol = lane & 15;
    const int g0   = lane >> 4;          // k-subslot 0..3
    const int r7   = lcol & 7;
    int aOff[8], bOff[4];
    #pragma unroll
    for (int m = 0; m < 8; ++m) {
        const int row = (m < 4) ? (wr * 64 + m * 16 + lcol)
                                : (128 + wr * 64 + (m - 4) * 16 + lcol);
        aOff[m] = row * 128;
    }
    #pragma unroll
    for (int n = 0; n < 4; ++n) {
        const int row = (n < 2) ? (wc * 32 + n * 16 + lcol)
                                : (128 + wc * 32 + (n - 2) * 16 + lcol);
        bOff[n] = 32768 + row * 128;
    }

    i32x4 acc[8][4] = {};

    // ---- prologue: stage tile 0 fully into buf 0, drain once ----
    STAGE_B(0, lds, 0) STAGE_B(1, lds, 0) STAGE_A(0, lds, 0) STAGE_A(1, lds, 0)
    __syncthreads();   // vmcnt(0) drain + barrier (one-time)

    // ---- K loop: per tile, 4 quadrant phases; counted vmcnt only ----
    for (int t = 0; t < NT; ++t) {
        const signed char* buf = lds + (t & 1) * 65536;
        signed char* nbuf      = lds + ((t & 1) ^ 1) * 65536;
        const long kn = (long)(t + 1) * 128;
        const bool more = (t + 1 < NT);
        i32x4 a0[4][2], a1[4][2], b0[2][2], b1[2][2];

        const int sw0 = (g0 ^ r7) << 4;            // ks=0 slot
        const int sw1 = ((4 + g0) ^ r7) << 4;      // ks=1 slot

        // ---- ph0: read A0 + B0; stage B0(t+1); MFMA m0-3 x n0-1 ----
        #pragma unroll
        for (int m = 0; m < 4; ++m) {
            a0[m][0] = *(const i32x4*)(buf + aOff[m] + sw0);
            a0[m][1] = *(const i32x4*)(buf + aOff[m] + sw1);
        }
        #pragma unroll
        for (int n = 0; n < 2; ++n) {
            b0[n][0] = *(const i32x4*)(buf + bOff[n] + sw0);
            b0[n][1] = *(const i32x4*)(buf + bOff[n] + sw1);
        }
        if (more) STAGE_B(0, nbuf, kn)
        __builtin_amdgcn_s_barrier();
        __builtin_amdgcn_s_setprio(1);
        #pragma unroll
        for (int m = 0; m < 4; ++m)
            #pragma unroll
            for (int n = 0; n < 2; ++n)
                #pragma unroll
                for (int k = 0; k < 2; ++k)
                    acc[m][n] = __builtin_amdgcn_mfma_i32_16x16x64_i8(
                        a0[m][k], b0[n][k], acc[m][n], 0, 0, 0);
        __builtin_amdgcn_s_setprio(0);
        __builtin_amdgcn_s_barrier();

        // ---- ph1: read B1; stage B1(t+1); vmcnt(4) guards A1(t) ----
        #pragma unroll
        for (int n = 0; n < 2; ++n) {
            b1[n][0] = *(const i32x4*)(buf + bOff[n + 2] + sw0);
            b1[n][1] = *(const i32x4*)(buf + bOff[n + 2] + sw1);
        }
        if (more) STAGE_B(1, nbuf, kn)
        asm volatile("s_waitcnt vmcnt(4)" ::: "memory");
        __builtin_amdgcn_sched_barrier(0);
        __builtin_amdgcn_s_barrier();
        __builtin_amdgcn_s_setprio(1);
        #pragma unroll
        for (int m = 0; m < 4; ++m)
            #pragma unroll
            for (int n = 0; n < 2; ++n)
                #pragma unroll
                for (int k = 0; k < 2; ++k)
                    acc[m][n + 2] = __builtin_amdgcn_mfma_i32_16x16x64_i8(
                        a0[m][k], b1[n][k], acc[m][n + 2], 0, 0, 0);
        __builtin_amdgcn_s_setprio(0);
        __builtin_amdgcn_s_barrier();

        // ---- ph2: read A1; stage A0(t+1); MFMA m4-7 x n0-1 ----
        #pragma unroll
        for (int m = 0; m < 4; ++m) {
            a1[m][0] = *(const i32x4*)(buf + aOff[m + 4] + sw0);
            a1[m][1] = *(const i32x4*)(buf + aOff[m + 4] + sw1);
        }
        if (more) STAGE_A(0, nbuf, kn)
        __builtin_amdgcn_s_barrier();
        __builtin_amdgcn_s_setprio(1);
        #pragma unroll
        for (int m = 0; m < 4; ++m)
            #pragma unroll
            for (int n = 0; n < 2; ++n)
                #pragma unroll
                for (int k = 0; k < 2; ++k)
                    acc[m + 4][n] = __builtin_amdgcn_mfma_i32_16x16x64_i8(
                        a1[m][k], b0[n][k], acc[m + 4][n], 0, 0, 0);
        __builtin_amdgcn_s_setprio(0);
        __builtin_amdgcn_s_barrier();

        // ---- ph3: stage A1(t+1); vmcnt(2) guards B0,B1,A0(t+1) ----
        if (more) STAGE_A(1, nbuf, kn)
        asm volatile("s_waitcnt vmcnt(2)" ::: "memory");
        __builtin_amdgcn_sched_barrier(0);
        __builtin_amdgcn_s_barrier();
        __builtin_amdgcn_s_setprio(1);
        #pragma unroll
        for (int m = 0; m < 4; ++m)
            #pragma unroll
            for (int n = 0; n < 2; ++n)
                #pragma unroll
                for (int k = 0; k < 2; ++k)
                    acc[m + 4][n + 2] = __builtin_amdgcn_mfma_i32_16x16x64_i8(
                        a1[m][k], b1[n][k], acc[m + 4][n + 2], 0, 0, 0);
        __builtin_amdgcn_s_setprio(0);
        __builtin_amdgcn_s_barrier();
    }

    // ---- epilogue: dequant + bias. C/D: col=lane&15, row=(lane>>4)*4+reg ----
    #pragma unroll
    for (int n = 0; n < 4; ++n) {
        const int col = bn * 256 + ((n < 2) ? (wc * 32 + n * 16)
                                            : (128 + wc * 32 + (n - 2) * 16)) + lcol;
        const float bv = bias[col];
        #pragma unroll
        for (int m = 0; m < 8; ++m) {
            const int row0 = bm * 256 + ((m < 4) ? (wr * 64 + m * 16)
                                                 : (128 + wr * 64 + (m - 4) * 16))
                             + (lane >> 4) * 4;
            #pragma unroll
            for (int i = 0; i < 4; ++i)
                out[(long)(row0 + i) * GN + col] = (float)acc[m][n][i] * s + bv;
        }
    }
    #undef STAGE_A
    #undef STAGE_B
}

// ---------------------------------------------------------------------------
extern "C" void kernel_launch(void* const* d_in, const int* in_sizes, int n_in,
                              void* d_out, int out_size, void* d_ws, size_t ws_size,
                              hipStream_t stream) {
    const float* x    = (const float*)d_in[0];
    const float* w    = (const float*)d_in[1];
    const float* bias = (const float*)d_in[2];
    float* out = (float*)d_out;

    const size_t need = 8192 + (size_t)GM * GK + (size_t)GN * GK;
    if (ws_size < need) return;

    float* partial   = (float*)d_ws + 4;
    signed char* xq  = (signed char*)d_ws + 8192;
    signed char* wq  = xq + (size_t)GM * GK;

    absmax_kernel<<<XBLK + WBLK, 256, 0, stream>>>(
        (const float4*)x, (const float4*)w, partial);
    quant_kernel<<<QXBLK + QWBLK, 256, 0, stream>>>(
        (const float4*)x, (const float4*)w, partial, (char4*)xq, (char4*)wq);
    gemm_kernel<<<(GM / 256) * (GN / 256), 512, 0, stream>>>(
        xq, wq, bias, partial, out);
}